// Round 7
// baseline (356.041 us; speedup 1.0000x reference)
//
#include <hip/hip_runtime.h>
#include <hip/hip_bf16.h>

#define E_N 640000
#define N_N 40000
#define SCAN_B 157  // ceil(40000/256)

typedef __attribute__((ext_vector_type(8))) short short8;
typedef __attribute__((ext_vector_type(4))) float f32x4;

static __device__ __forceinline__ unsigned short f2bf(float f) {
  __hip_bfloat16 h = __float2bfloat16(f);
  unsigned short u;
  __builtin_memcpy(&u, &h, 2);
  return u;
}
static __device__ __forceinline__ float bf2f(unsigned short u) {
  return __uint_as_float(((unsigned int)u) << 16);
}

// ---------------- Wt[layer][k][o][i] = bf16(W[k][i][o]), both layers in one dispatch ----------------
__global__ __launch_bounds__(256) void wtrans_kernel(
    const float* __restrict__ W1, const float* __restrict__ W2,
    unsigned short* __restrict__ Wt) {  // Wt: [2][25][64][64]
  int t = blockIdx.x * 256 + threadIdx.x;  // 0..204799
  int half = t >= 102400;
  int r = t - (half ? 102400 : 0);
  const float* W = half ? W2 : W1;
  int k = r >> 12, rr = r & 4095, o = rr >> 6, i = rr & 63;
  Wt[((size_t)half * 102400) + (k << 12) + (o << 6) + i] = f2bf(W[(k << 12) + (i << 6) + o]);
}

// ---------------- Y[n,k,o] via MFMA: C[o][node] = Wt_rows x x_cols ----------------
__global__ __launch_bounds__(256) void ygemm_kernel(
    const float* __restrict__ x, const unsigned short* __restrict__ Wt,
    unsigned short* __restrict__ Y) {
  const int n0 = blockIdx.x * 64;
  const int w = threadIdx.x >> 6;
  const int l = threadIdx.x & 63;
  const int lr = l & 15;
  const int lh = l >> 4;

  short8 bx[4][2];
  #pragma unroll
  for (int nt = 0; nt < 4; ++nt) {
    const float* xp = x + ((size_t)(n0 + nt * 16 + lr) << 6) + (lh << 3);
    #pragma unroll
    for (int h = 0; h < 2; ++h) {
      float4 lo = *(const float4*)(xp + h * 32);
      float4 hi = *(const float4*)(xp + h * 32 + 4);
      short8 b;
      b[0] = (short)f2bf(lo.x); b[1] = (short)f2bf(lo.y);
      b[2] = (short)f2bf(lo.z); b[3] = (short)f2bf(lo.w);
      b[4] = (short)f2bf(hi.x); b[5] = (short)f2bf(hi.y);
      b[6] = (short)f2bf(hi.z); b[7] = (short)f2bf(hi.w);
      bx[nt][h] = b;
    }
  }

  const f32x4 Z = {0.0f, 0.0f, 0.0f, 0.0f};

  for (int k = w; k < 25; k += 4) {
    const unsigned short* wk = Wt + ((size_t)k << 12);
    short8 aw[4][2];
    #pragma unroll
    for (int ot = 0; ot < 4; ++ot)
      #pragma unroll
      for (int h = 0; h < 2; ++h)
        aw[ot][h] = *(const short8*)(wk + ((ot * 16 + lr) << 6) + (h << 5) + (lh << 3));

    f32x4 acc[4][4];
    #pragma unroll
    for (int ot = 0; ot < 4; ++ot)
      #pragma unroll
      for (int nt = 0; nt < 4; ++nt) {
        acc[ot][nt] = __builtin_amdgcn_mfma_f32_16x16x32_bf16(aw[ot][0], bx[nt][0], Z, 0, 0, 0);
        acc[ot][nt] = __builtin_amdgcn_mfma_f32_16x16x32_bf16(aw[ot][1], bx[nt][1], acc[ot][nt], 0, 0, 0);
      }

    #pragma unroll
    for (int ot = 0; ot < 4; ++ot)
      #pragma unroll
      for (int nt = 0; nt < 4; ++nt) {
        int node = n0 + nt * 16 + lr;
        int o = ot * 16 + (lh << 2);
        unsigned int p0 = (unsigned)f2bf(acc[ot][nt][0]) | ((unsigned)f2bf(acc[ot][nt][1]) << 16);
        unsigned int p1 = (unsigned)f2bf(acc[ot][nt][2]) | ((unsigned)f2bf(acc[ot][nt][3]) << 16);
        uint2 p; p.x = p0; p.y = p1;
        *(uint2*)(Y + ((size_t)node * 25 + k) * 64 + o) = p;
      }
  }
}

// ---------------- CSR build: histogram -> 3-stage parallel scan -> scatter ----------------
__global__ __launch_bounds__(256) void hist_kernel(
    const int* __restrict__ ei, int* __restrict__ cnt) {
  int e = blockIdx.x * 256 + threadIdx.x;
  atomicAdd(&cnt[ei[E_N + e]], 1);
}

__global__ __launch_bounds__(256) void scan1_kernel(
    const int* __restrict__ cnt, int* __restrict__ bsum) {
  __shared__ int red[256];
  int t = threadIdx.x;
  int j = blockIdx.x * 256 + t;
  red[t] = (j < N_N) ? cnt[j] : 0;
  __syncthreads();
  #pragma unroll
  for (int s = 128; s > 0; s >>= 1) {
    if (t < s) red[t] += red[t + s];
    __syncthreads();
  }
  if (t == 0) bsum[blockIdx.x] = red[0];
}

__global__ __launch_bounds__(256) void scan2_kernel(
    const int* __restrict__ bsum, int* __restrict__ bofs) {
  __shared__ int v[256];
  int t = threadIdx.x;
  v[t] = (t < SCAN_B) ? bsum[t] : 0;
  __syncthreads();
  if (t == 0) {
    int acc = 0;
    for (int i = 0; i < SCAN_B; ++i) { int c = v[i]; v[i] = acc; acc += c; }
  }
  __syncthreads();
  if (t < SCAN_B) bofs[t] = v[t];
}

// in-block exclusive scan + block offset -> start; ofs written in-place into cnt
__global__ __launch_bounds__(256) void scan3_kernel(
    int* __restrict__ cnt, const int* __restrict__ bofs,
    int* __restrict__ start) {
  __shared__ int v[2][256];
  int t = threadIdx.x;
  int j = blockIdx.x * 256 + t;
  int c = (j < N_N) ? cnt[j] : 0;
  v[0][t] = c;
  __syncthreads();
  int cur = 0;
  #pragma unroll
  for (int s = 1; s < 256; s <<= 1) {
    v[1 - cur][t] = (t >= s) ? v[cur][t] + v[cur][t - s] : v[cur][t];
    __syncthreads();
    cur = 1 - cur;
  }
  if (j < N_N) {
    int ex = bofs[blockIdx.x] + v[cur][t] - c;
    start[j] = ex;
    cnt[j] = ex;  // becomes the scatter cursor
    if (j == 0) start[N_N] = E_N;
  }
}

// recs: uint4 { src | I0<<16, bf16(b0)|bf16(b1)<<16, bf16(b2)|bf16(b3)<<16, 0 }
__global__ __launch_bounds__(256) void scatter_kernel(
    const float* __restrict__ ea, const int* __restrict__ ei,
    int* __restrict__ ofs, uint4* __restrict__ recs) {
  int e = blockIdx.x * 256 + threadIdx.x;
  int s = ei[e];
  int d = ei[E_N + e];
  float2 a = ((const float2*)ea)[e];
  float v0 = a.x * 4.0f, v1 = a.y * 4.0f;
  float b0f = fminf(fmaxf(floorf(v0), 0.0f), 3.0f);
  float b1f = fminf(fmaxf(floorf(v1), 0.0f), 3.0f);
  float f0 = v0 - b0f, f1 = v1 - b1f;
  int I0 = (int)b0f * 5 + (int)b1f;
  float b0 = (1.0f - f0) * (1.0f - f1);
  float b1 = (1.0f - f0) * f1;
  float b2 = f0 * (1.0f - f1);
  float b3 = f0 * f1;
  int pos = atomicAdd(&ofs[d], 1);
  uint4 rc;
  rc.x = (unsigned int)s | ((unsigned int)I0 << 16);
  rc.y = (unsigned int)f2bf(b0) | ((unsigned int)f2bf(b1) << 16);
  rc.z = (unsigned int)f2bf(b2) | ((unsigned int)f2bf(b3) << 16);
  rc.w = 0u;
  recs[pos] = rc;
}

// ---------------- agg (one wave per dst node, 8 indep max chains) + fused epilogue ----------------
static __device__ __forceinline__ float emsg(
    const unsigned short* __restrict__ Y, uint4 rc, int lane) {
  const unsigned short* base =
      Y + (size_t)(rc.x & 0xffffu) * 1600 + (rc.x >> 16) * 64 + lane;
  float y0 = bf2f(base[0]);
  float y1 = bf2f(base[64]);
  float y2 = bf2f(base[320]);
  float y3 = bf2f(base[384]);
  float b0 = __uint_as_float(rc.y << 16);
  float b1 = __uint_as_float(rc.y & 0xffff0000u);
  float b2 = __uint_as_float(rc.z << 16);
  float b3 = __uint_as_float(rc.z & 0xffff0000u);
  return fmaf(b0, y0, fmaf(b1, y1, fmaf(b2, y2, b3 * y3)));
}

__global__ __launch_bounds__(256) void agg_kernel(
    const unsigned short* __restrict__ Y, const uint4* __restrict__ recs,
    const int* __restrict__ start, const float* __restrict__ xin,
    const float* __restrict__ root, const float* __restrict__ bias,
    float* __restrict__ outp, int relu) {
  __shared__ float xl[4][64];
  const int w = threadIdx.x >> 6;
  const int lane = threadIdx.x & 63;
  const int n = blockIdx.x * 4 + w;
  xl[w][lane] = xin[((size_t)n << 6) + lane];
  __syncthreads();

  const int s = start[n];
  const int e = start[n + 1];
  const float NI = -__builtin_inff();
  float a[8];
  #pragma unroll
  for (int u = 0; u < 8; ++u) a[u] = NI;

  int j = s;
  for (; j + 8 <= e; j += 8) {
    uint4 rc[8];
    #pragma unroll
    for (int u = 0; u < 8; ++u) rc[u] = recs[j + u];
    #pragma unroll
    for (int u = 0; u < 8; ++u) a[u] = fmaxf(a[u], emsg(Y, rc[u], lane));
  }
  for (; j + 4 <= e; j += 4) {
    uint4 rc[4];
    #pragma unroll
    for (int u = 0; u < 4; ++u) rc[u] = recs[j + u];
    #pragma unroll
    for (int u = 0; u < 4; ++u) a[u] = fmaxf(a[u], emsg(Y, rc[u], lane));
  }
  for (; j < e; ++j) a[0] = fmaxf(a[0], emsg(Y, recs[j], lane));

  float acc = fmaxf(fmaxf(fmaxf(a[0], a[1]), fmaxf(a[2], a[3])),
                    fmaxf(fmaxf(a[4], a[5]), fmaxf(a[6], a[7])));
  if (s == e) acc = 0.0f;

  float r = bias[lane];
  #pragma unroll 8
  for (int i = 0; i < 64; ++i)
    r += xl[w][i] * root[(i << 6) + lane];
  r += acc;
  if (relu) r = fmaxf(r, 0.0f);
  outp[((size_t)n << 6) + lane] = r;
}

extern "C" void kernel_launch(void* const* d_in, const int* in_sizes, int n_in,
                              void* d_out, int out_size, void* d_ws, size_t ws_size,
                              hipStream_t stream) {
  const float* x = (const float*)d_in[0];
  const int* ei = (const int*)d_in[1];
  const float* ea = (const float*)d_in[2];
  const float* W1 = (const float*)d_in[3];
  const float* root1 = (const float*)d_in[4];
  const float* bias1 = (const float*)d_in[5];
  const float* W2 = (const float*)d_in[6];
  const float* root2 = (const float*)d_in[7];
  const float* bias2 = (const float*)d_in[8];
  float* out = (float*)d_out;

  const size_t yB = (size_t)N_N * 1600 * 2;    // 128,000,000
  const size_t rB = (size_t)E_N * 16;          //  10,240,000
  const size_t sB = (size_t)(N_N + 2) * 4;     //     160,008 (padded for alignment)
  const size_t cB = (size_t)N_N * 4;           //     160,000 (cnt, reused as ofs)
  const size_t wB = (size_t)2 * 25 * 64 * 64 * 2;  // 409,600 (Wt1|Wt2)
  const size_t bB = (size_t)1024 * 2;          //       2,048 (bsum|bofs)
  if (ws_size < yB + rB + sB + cB + wB + bB) return;

  char* p = (char*)d_ws;
  unsigned short* Y = (unsigned short*)p; p += yB;
  uint4* recs = (uint4*)p;                p += rB;
  int* startA = (int*)p;                  p += sB;
  int* cnt = (int*)p;                     p += cB;   // doubles as scatter cursor
  unsigned short* Wt = (unsigned short*)p; p += wB;  // Wt1 then Wt2
  int* bsum = (int*)p;                    p += 1024;
  int* bofs = (int*)p;
  float* h = out;  // layer-1 output lives in d_out; fully overwritten by layer 2

  unsigned short* Wt1 = Wt;
  unsigned short* Wt2 = Wt + (size_t)25 * 64 * 64;

  dim3 blk(256);

  // ---- CSR build (once, shared by both layers) + both weight transposes ----
  hipMemsetAsync(cnt, 0, cB, stream);
  wtrans_kernel<<<800, blk, 0, stream>>>(W1, W2, Wt);
  hist_kernel<<<E_N / 256, blk, 0, stream>>>(ei, cnt);
  scan1_kernel<<<SCAN_B, blk, 0, stream>>>(cnt, bsum);
  scan2_kernel<<<1, blk, 0, stream>>>(bsum, bofs);
  scan3_kernel<<<SCAN_B, blk, 0, stream>>>(cnt, bofs, startA);
  scatter_kernel<<<E_N / 256, blk, 0, stream>>>(ea, ei, cnt, recs);

  // ---- layer 1 ----
  ygemm_kernel<<<N_N / 64, blk, 0, stream>>>(x, Wt1, Y);
  agg_kernel<<<N_N / 4, blk, 0, stream>>>(Y, recs, startA, x, root1, bias1, h, 1);

  // ---- layer 2 ----
  ygemm_kernel<<<N_N / 64, blk, 0, stream>>>(h, Wt2, Y);
  agg_kernel<<<N_N / 4, blk, 0, stream>>>(Y, recs, startA, h, root2, bias2, out, 0);
}

// Round 8
// 311.111 us; speedup vs baseline: 1.1444x; 1.1444x over previous
//
#include <hip/hip_runtime.h>
#include <hip/hip_bf16.h>

#define E_N 640000
#define N_N 40000
#define SCAN_B 157  // ceil(40000/256)

typedef __attribute__((ext_vector_type(8))) short short8;
typedef __attribute__((ext_vector_type(4))) float f32x4;

static __device__ __forceinline__ unsigned short f2bf(float f) {
  __hip_bfloat16 h = __float2bfloat16(f);
  unsigned short u;
  __builtin_memcpy(&u, &h, 2);
  return u;
}
static __device__ __forceinline__ float bf2f(unsigned short u) {
  return __uint_as_float(((unsigned int)u) << 16);
}

// ---------------- Wt[layer][k][o][i] = bf16(W[k][i][o]), both layers in one dispatch ----------------
__global__ __launch_bounds__(256) void wtrans_kernel(
    const float* __restrict__ W1, const float* __restrict__ W2,
    unsigned short* __restrict__ Wt) {  // Wt: [2][25][64][64]
  int t = blockIdx.x * 256 + threadIdx.x;  // 0..204799
  int half = t >= 102400;
  int r = t - (half ? 102400 : 0);
  const float* W = half ? W2 : W1;
  int k = r >> 12, rr = r & 4095, o = rr >> 6, i = rr & 63;
  Wt[((size_t)half * 102400) + (k << 12) + (o << 6) + i] = f2bf(W[(k << 12) + (i << 6) + o]);
}

// ---------------- Y[n,k,o] via MFMA: C[o][node] = Wt_rows x x_cols ----------------
__global__ __launch_bounds__(256) void ygemm_kernel(
    const float* __restrict__ x, const unsigned short* __restrict__ Wt,
    unsigned short* __restrict__ Y) {
  const int n0 = blockIdx.x * 64;
  const int w = threadIdx.x >> 6;
  const int l = threadIdx.x & 63;
  const int lr = l & 15;
  const int lh = l >> 4;

  short8 bx[4][2];
  #pragma unroll
  for (int nt = 0; nt < 4; ++nt) {
    const float* xp = x + ((size_t)(n0 + nt * 16 + lr) << 6) + (lh << 3);
    #pragma unroll
    for (int h = 0; h < 2; ++h) {
      float4 lo = *(const float4*)(xp + h * 32);
      float4 hi = *(const float4*)(xp + h * 32 + 4);
      short8 b;
      b[0] = (short)f2bf(lo.x); b[1] = (short)f2bf(lo.y);
      b[2] = (short)f2bf(lo.z); b[3] = (short)f2bf(lo.w);
      b[4] = (short)f2bf(hi.x); b[5] = (short)f2bf(hi.y);
      b[6] = (short)f2bf(hi.z); b[7] = (short)f2bf(hi.w);
      bx[nt][h] = b;
    }
  }

  const f32x4 Z = {0.0f, 0.0f, 0.0f, 0.0f};

  for (int k = w; k < 25; k += 4) {
    const unsigned short* wk = Wt + ((size_t)k << 12);
    short8 aw[4][2];
    #pragma unroll
    for (int ot = 0; ot < 4; ++ot)
      #pragma unroll
      for (int h = 0; h < 2; ++h)
        aw[ot][h] = *(const short8*)(wk + ((ot * 16 + lr) << 6) + (h << 5) + (lh << 3));

    f32x4 acc[4][4];
    #pragma unroll
    for (int ot = 0; ot < 4; ++ot)
      #pragma unroll
      for (int nt = 0; nt < 4; ++nt) {
        acc[ot][nt] = __builtin_amdgcn_mfma_f32_16x16x32_bf16(aw[ot][0], bx[nt][0], Z, 0, 0, 0);
        acc[ot][nt] = __builtin_amdgcn_mfma_f32_16x16x32_bf16(aw[ot][1], bx[nt][1], acc[ot][nt], 0, 0, 0);
      }

    #pragma unroll
    for (int ot = 0; ot < 4; ++ot)
      #pragma unroll
      for (int nt = 0; nt < 4; ++nt) {
        int node = n0 + nt * 16 + lr;
        int o = ot * 16 + (lh << 2);
        unsigned int p0 = (unsigned)f2bf(acc[ot][nt][0]) | ((unsigned)f2bf(acc[ot][nt][1]) << 16);
        unsigned int p1 = (unsigned)f2bf(acc[ot][nt][2]) | ((unsigned)f2bf(acc[ot][nt][3]) << 16);
        uint2 p; p.x = p0; p.y = p1;
        *(uint2*)(Y + ((size_t)node * 25 + k) * 64 + o) = p;
      }
  }
}

// ---------------- CSR build: histogram -> 3-stage parallel scan -> scatter ----------------
__global__ __launch_bounds__(256) void hist_kernel(
    const int* __restrict__ ei, int* __restrict__ cnt) {
  int e = blockIdx.x * 256 + threadIdx.x;
  atomicAdd(&cnt[ei[E_N + e]], 1);
}

__global__ __launch_bounds__(256) void scan1_kernel(
    const int* __restrict__ cnt, int* __restrict__ bsum) {
  __shared__ int red[256];
  int t = threadIdx.x;
  int j = blockIdx.x * 256 + t;
  red[t] = (j < N_N) ? cnt[j] : 0;
  __syncthreads();
  #pragma unroll
  for (int s = 128; s > 0; s >>= 1) {
    if (t < s) red[t] += red[t + s];
    __syncthreads();
  }
  if (t == 0) bsum[blockIdx.x] = red[0];
}

__global__ __launch_bounds__(256) void scan2_kernel(
    const int* __restrict__ bsum, int* __restrict__ bofs) {
  __shared__ int v[256];
  int t = threadIdx.x;
  v[t] = (t < SCAN_B) ? bsum[t] : 0;
  __syncthreads();
  if (t == 0) {
    int acc = 0;
    for (int i = 0; i < SCAN_B; ++i) { int c = v[i]; v[i] = acc; acc += c; }
  }
  __syncthreads();
  if (t < SCAN_B) bofs[t] = v[t];
}

__global__ __launch_bounds__(256) void scan3_kernel(
    int* __restrict__ cnt, const int* __restrict__ bofs,
    int* __restrict__ start) {
  __shared__ int v[2][256];
  int t = threadIdx.x;
  int j = blockIdx.x * 256 + t;
  int c = (j < N_N) ? cnt[j] : 0;
  v[0][t] = c;
  __syncthreads();
  int cur = 0;
  #pragma unroll
  for (int s = 1; s < 256; s <<= 1) {
    v[1 - cur][t] = (t >= s) ? v[cur][t] + v[cur][t - s] : v[cur][t];
    __syncthreads();
    cur = 1 - cur;
  }
  if (j < N_N) {
    int ex = bofs[blockIdx.x] + v[cur][t] - c;
    start[j] = ex;
    cnt[j] = ex;  // becomes the scatter cursor
    if (j == 0) start[N_N] = E_N;
  }
}

// recs: uint2 { src | I0<<16, q0 | q1<<16 }  (q = 16-bit fixed-point frac)
__global__ __launch_bounds__(256) void scatter_kernel(
    const float* __restrict__ ea, const int* __restrict__ ei,
    int* __restrict__ ofs, uint2* __restrict__ recs) {
  int e = blockIdx.x * 256 + threadIdx.x;
  int s = ei[e];
  int d = ei[E_N + e];
  float2 a = ((const float2*)ea)[e];
  float v0 = a.x * 4.0f, v1 = a.y * 4.0f;
  float b0f = fminf(fmaxf(floorf(v0), 0.0f), 3.0f);
  float b1f = fminf(fmaxf(floorf(v1), 0.0f), 3.0f);
  float f0 = v0 - b0f, f1 = v1 - b1f;
  int I0 = (int)b0f * 5 + (int)b1f;
  unsigned int q0 = (unsigned int)(f0 * 65535.0f + 0.5f);
  unsigned int q1 = (unsigned int)(f1 * 65535.0f + 0.5f);
  int pos = atomicAdd(&ofs[d], 1);
  uint2 rc;
  rc.x = (unsigned int)s | ((unsigned int)I0 << 16);
  rc.y = q0 | (q1 << 16);
  recs[pos] = rc;
}

// ---------------- agg (one wave per dst node, 4 indep max chains, scalarized) ----------------
static __device__ __forceinline__ float emsg(
    const unsigned short* __restrict__ Y, unsigned int rx, unsigned int ry, int lane) {
  // rx, ry are wave-uniform (readfirstlane'd) -> address math on SALU
  int src = rx & 0xffff;
  int I0 = rx >> 16;
  float f0 = (float)(ry & 0xffff) * (1.0f / 65535.0f);
  float f1 = (float)(ry >> 16) * (1.0f / 65535.0f);
  const unsigned short* base = Y + (size_t)src * 1600 + I0 * 64 + lane;
  float y0 = bf2f(base[0]);
  float y1 = bf2f(base[64]);
  float y2 = bf2f(base[320]);
  float y3 = bf2f(base[384]);
  return (1.0f - f0) * ((1.0f - f1) * y0 + f1 * y1) +
         f0 * ((1.0f - f1) * y2 + f1 * y3);
}

__global__ __launch_bounds__(256) void agg_kernel(
    const unsigned short* __restrict__ Y, const uint2* __restrict__ recs,
    const int* __restrict__ start, const float* __restrict__ xin,
    const float* __restrict__ root, const float* __restrict__ bias,
    float* __restrict__ outp, int relu) {
  __shared__ float xl[4][64];
  const int w = threadIdx.x >> 6;
  const int lane = threadIdx.x & 63;
  const int n = blockIdx.x * 4 + w;
  xl[w][lane] = xin[((size_t)n << 6) + lane];
  __syncthreads();

  // wave-uniform CSR bounds in SGPRs -> recs loads become scalar loads
  const int s = __builtin_amdgcn_readfirstlane(start[n]);
  const int e = __builtin_amdgcn_readfirstlane(start[n + 1]);
  const float NI = -__builtin_inff();
  float a0 = NI, a1 = NI, a2 = NI, a3 = NI;
  int j = s;
  for (; j + 4 <= e; j += 4) {
    uint2 r0 = recs[j];
    uint2 r1 = recs[j + 1];
    uint2 r2 = recs[j + 2];
    uint2 r3 = recs[j + 3];
    unsigned x0 = __builtin_amdgcn_readfirstlane(r0.x), y0 = __builtin_amdgcn_readfirstlane(r0.y);
    unsigned x1 = __builtin_amdgcn_readfirstlane(r1.x), y1 = __builtin_amdgcn_readfirstlane(r1.y);
    unsigned x2 = __builtin_amdgcn_readfirstlane(r2.x), y2 = __builtin_amdgcn_readfirstlane(r2.y);
    unsigned x3 = __builtin_amdgcn_readfirstlane(r3.x), y3 = __builtin_amdgcn_readfirstlane(r3.y);
    float m0 = emsg(Y, x0, y0, lane);
    float m1 = emsg(Y, x1, y1, lane);
    float m2 = emsg(Y, x2, y2, lane);
    float m3 = emsg(Y, x3, y3, lane);
    a0 = fmaxf(a0, m0);
    a1 = fmaxf(a1, m1);
    a2 = fmaxf(a2, m2);
    a3 = fmaxf(a3, m3);
  }
  for (; j < e; ++j) {
    uint2 rc = recs[j];
    unsigned rx = __builtin_amdgcn_readfirstlane(rc.x);
    unsigned ry = __builtin_amdgcn_readfirstlane(rc.y);
    a0 = fmaxf(a0, emsg(Y, rx, ry, lane));
  }
  float acc = fmaxf(fmaxf(a0, a1), fmaxf(a2, a3));
  if (s == e) acc = 0.0f;

  float r = bias[lane];
  #pragma unroll 8
  for (int i = 0; i < 64; ++i)
    r += xl[w][i] * root[(i << 6) + lane];
  r += acc;
  if (relu) r = fmaxf(r, 0.0f);
  outp[((size_t)n << 6) + lane] = r;
}

extern "C" void kernel_launch(void* const* d_in, const int* in_sizes, int n_in,
                              void* d_out, int out_size, void* d_ws, size_t ws_size,
                              hipStream_t stream) {
  const float* x = (const float*)d_in[0];
  const int* ei = (const int*)d_in[1];
  const float* ea = (const float*)d_in[2];
  const float* W1 = (const float*)d_in[3];
  const float* root1 = (const float*)d_in[4];
  const float* bias1 = (const float*)d_in[5];
  const float* W2 = (const float*)d_in[6];
  const float* root2 = (const float*)d_in[7];
  const float* bias2 = (const float*)d_in[8];
  float* out = (float*)d_out;

  const size_t yB = (size_t)N_N * 1600 * 2;        // 128,000,000
  const size_t rB = (size_t)E_N * 8;               //   5,120,000
  const size_t sB = (size_t)(N_N + 2) * 4;         //     160,008
  const size_t cB = (size_t)N_N * 4;               //     160,000
  const size_t wB = (size_t)2 * 25 * 64 * 64 * 2;  //     409,600
  const size_t bB = (size_t)1024 * 2;
  if (ws_size < yB + rB + sB + cB + wB + bB) return;

  char* p = (char*)d_ws;
  unsigned short* Y = (unsigned short*)p; p += yB;
  uint2* recs = (uint2*)p;                p += rB;
  int* startA = (int*)p;                  p += sB;
  int* cnt = (int*)p;                     p += cB;   // doubles as scatter cursor
  unsigned short* Wt = (unsigned short*)p; p += wB;  // Wt1 | Wt2
  int* bsum = (int*)p;                    p += 1024;
  int* bofs = (int*)p;
  float* h = out;  // layer-1 output lives in d_out; fully overwritten by layer 2

  unsigned short* Wt1 = Wt;
  unsigned short* Wt2 = Wt + (size_t)25 * 64 * 64;

  dim3 blk(256);

  // ---- CSR build (once, shared by both layers) + both weight transposes ----
  hipMemsetAsync(cnt, 0, cB, stream);
  wtrans_kernel<<<800, blk, 0, stream>>>(W1, W2, Wt);
  hist_kernel<<<E_N / 256, blk, 0, stream>>>(ei, cnt);
  scan1_kernel<<<SCAN_B, blk, 0, stream>>>(cnt, bsum);
  scan2_kernel<<<1, blk, 0, stream>>>(bsum, bofs);
  scan3_kernel<<<SCAN_B, blk, 0, stream>>>(cnt, bofs, startA);
  scatter_kernel<<<E_N / 256, blk, 0, stream>>>(ea, ei, cnt, recs);

  // ---- layer 1 ----
  ygemm_kernel<<<N_N / 64, blk, 0, stream>>>(x, Wt1, Y);
  agg_kernel<<<N_N / 4, blk, 0, stream>>>(Y, recs, startA, x, root1, bias1, h, 1);

  // ---- layer 2 ----
  ygemm_kernel<<<N_N / 64, blk, 0, stream>>>(h, Wt2, Y);
  agg_kernel<<<N_N / 4, blk, 0, stream>>>(Y, recs, startA, h, root2, bias2, out, 0);
}

// Round 9
// 268.744 us; speedup vs baseline: 1.3248x; 1.1576x over previous
//
#include <hip/hip_runtime.h>
#include <hip/hip_bf16.h>

#define E_N 640000
#define N_N 40000
#define SCAN_B 157  // ceil(40000/256)

typedef __attribute__((ext_vector_type(8))) short short8;
typedef __attribute__((ext_vector_type(4))) float f32x4;

static __device__ __forceinline__ unsigned short f2bf(float f) {
  __hip_bfloat16 h = __float2bfloat16(f);
  unsigned short u;
  __builtin_memcpy(&u, &h, 2);
  return u;
}
static __device__ __forceinline__ float bf2f(unsigned short u) {
  return __uint_as_float(((unsigned int)u) << 16);
}

// ---------------- Wt[layer][k][o][i] = bf16(W[k][i][o]), both layers in one dispatch ----------------
__global__ __launch_bounds__(256) void wtrans_kernel(
    const float* __restrict__ W1, const float* __restrict__ W2,
    unsigned short* __restrict__ Wt) {  // Wt: [2][25][64][64]
  int t = blockIdx.x * 256 + threadIdx.x;  // 0..204799
  int half = t >= 102400;
  int r = t - (half ? 102400 : 0);
  const float* W = half ? W2 : W1;
  int k = r >> 12, rr = r & 4095, o = rr >> 6, i = rr & 63;
  Wt[((size_t)half * 102400) + (k << 12) + (o << 6) + i] = f2bf(W[(k << 12) + (i << 6) + o]);
}

// ---------------- Y[n,k,o] via MFMA: C[o][node] = Wt_rows x x_cols ----------------
// writeout staged through wave-private LDS so every global store instruction
// covers full 128B cache lines (kills L2 write-allocate RMW fetch of Y)
__global__ __launch_bounds__(256) void ygemm_kernel(
    const float* __restrict__ x, const unsigned short* __restrict__ Wt,
    unsigned short* __restrict__ Y) {
  __shared__ unsigned short tile[4][64 * 72];  // stride 144B (16B-aligned)
  const int n0 = blockIdx.x * 64;
  const int w = threadIdx.x >> 6;
  const int l = threadIdx.x & 63;
  const int lr = l & 15;
  const int lh = l >> 4;
  unsigned short* tl = tile[w];

  short8 bx[4][2];
  #pragma unroll
  for (int nt = 0; nt < 4; ++nt) {
    const float* xp = x + ((size_t)(n0 + nt * 16 + lr) << 6) + (lh << 3);
    #pragma unroll
    for (int h = 0; h < 2; ++h) {
      float4 lo = *(const float4*)(xp + h * 32);
      float4 hi = *(const float4*)(xp + h * 32 + 4);
      short8 b;
      b[0] = (short)f2bf(lo.x); b[1] = (short)f2bf(lo.y);
      b[2] = (short)f2bf(lo.z); b[3] = (short)f2bf(lo.w);
      b[4] = (short)f2bf(hi.x); b[5] = (short)f2bf(hi.y);
      b[6] = (short)f2bf(hi.z); b[7] = (short)f2bf(hi.w);
      bx[nt][h] = b;
    }
  }

  const f32x4 Z = {0.0f, 0.0f, 0.0f, 0.0f};

  for (int k = w; k < 25; k += 4) {
    const unsigned short* wk = Wt + ((size_t)k << 12);
    short8 aw[4][2];
    #pragma unroll
    for (int ot = 0; ot < 4; ++ot)
      #pragma unroll
      for (int h = 0; h < 2; ++h)
        aw[ot][h] = *(const short8*)(wk + ((ot * 16 + lr) << 6) + (h << 5) + (lh << 3));

    f32x4 acc[4][4];
    #pragma unroll
    for (int ot = 0; ot < 4; ++ot)
      #pragma unroll
      for (int nt = 0; nt < 4; ++nt) {
        acc[ot][nt] = __builtin_amdgcn_mfma_f32_16x16x32_bf16(aw[ot][0], bx[nt][0], Z, 0, 0, 0);
        acc[ot][nt] = __builtin_amdgcn_mfma_f32_16x16x32_bf16(aw[ot][1], bx[nt][1], acc[ot][nt], 0, 0, 0);
      }

    // pack C into per-wave LDS tile [node][o], row stride 72 shorts
    #pragma unroll
    for (int ot = 0; ot < 4; ++ot)
      #pragma unroll
      for (int nt = 0; nt < 4; ++nt) {
        int node = nt * 16 + lr;
        int o = ot * 16 + (lh << 2);
        uint2 p;
        p.x = (unsigned)f2bf(acc[ot][nt][0]) | ((unsigned)f2bf(acc[ot][nt][1]) << 16);
        p.y = (unsigned)f2bf(acc[ot][nt][2]) | ((unsigned)f2bf(acc[ot][nt][3]) << 16);
        *(uint2*)(tl + node * 72 + o) = p;
      }

    // copy out: each instruction writes 8 complete 128B lines
    #pragma unroll
    for (int r8 = 0; r8 < 8; ++r8) {
      int node = r8 * 8 + (l >> 3);
      int c = (l & 7) << 3;  // o offset in shorts, 16B chunk
      uint4 v = *(const uint4*)(tl + node * 72 + c);
      *(uint4*)(Y + ((size_t)(n0 + node) * 25 + k) * 64 + c) = v;
    }
  }
}

// ---------------- CSR build: histogram -> 3-stage parallel scan -> scatter ----------------
__global__ __launch_bounds__(256) void hist_kernel(
    const int* __restrict__ ei, int* __restrict__ cnt) {
  int e = blockIdx.x * 256 + threadIdx.x;
  atomicAdd(&cnt[ei[E_N + e]], 1);
}

__global__ __launch_bounds__(256) void scan1_kernel(
    const int* __restrict__ cnt, int* __restrict__ bsum) {
  __shared__ int red[256];
  int t = threadIdx.x;
  int j = blockIdx.x * 256 + t;
  red[t] = (j < N_N) ? cnt[j] : 0;
  __syncthreads();
  #pragma unroll
  for (int s = 128; s > 0; s >>= 1) {
    if (t < s) red[t] += red[t + s];
    __syncthreads();
  }
  if (t == 0) bsum[blockIdx.x] = red[0];
}

__global__ __launch_bounds__(256) void scan2_kernel(
    const int* __restrict__ bsum, int* __restrict__ bofs) {
  __shared__ int v[256];
  int t = threadIdx.x;
  v[t] = (t < SCAN_B) ? bsum[t] : 0;
  __syncthreads();
  if (t == 0) {
    int acc = 0;
    for (int i = 0; i < SCAN_B; ++i) { int c = v[i]; v[i] = acc; acc += c; }
  }
  __syncthreads();
  if (t < SCAN_B) bofs[t] = v[t];
}

__global__ __launch_bounds__(256) void scan3_kernel(
    int* __restrict__ cnt, const int* __restrict__ bofs,
    int* __restrict__ start) {
  __shared__ int v[2][256];
  int t = threadIdx.x;
  int j = blockIdx.x * 256 + t;
  int c = (j < N_N) ? cnt[j] : 0;
  v[0][t] = c;
  __syncthreads();
  int cur = 0;
  #pragma unroll
  for (int s = 1; s < 256; s <<= 1) {
    v[1 - cur][t] = (t >= s) ? v[cur][t] + v[cur][t - s] : v[cur][t];
    __syncthreads();
    cur = 1 - cur;
  }
  if (j < N_N) {
    int ex = bofs[blockIdx.x] + v[cur][t] - c;
    start[j] = ex;
    cnt[j] = ex;  // becomes the scatter cursor
    if (j == 0) start[N_N] = E_N;
  }
}

// recs: uint2 { src | I0<<16, q0 | q1<<16 }  (q = 16-bit fixed-point frac)
__global__ __launch_bounds__(256) void scatter_kernel(
    const float* __restrict__ ea, const int* __restrict__ ei,
    int* __restrict__ ofs, uint2* __restrict__ recs) {
  int e = blockIdx.x * 256 + threadIdx.x;
  int s = ei[e];
  int d = ei[E_N + e];
  float2 a = ((const float2*)ea)[e];
  float v0 = a.x * 4.0f, v1 = a.y * 4.0f;
  float b0f = fminf(fmaxf(floorf(v0), 0.0f), 3.0f);
  float b1f = fminf(fmaxf(floorf(v1), 0.0f), 3.0f);
  float f0 = v0 - b0f, f1 = v1 - b1f;
  int I0 = (int)b0f * 5 + (int)b1f;
  unsigned int q0 = (unsigned int)(f0 * 65535.0f + 0.5f);
  unsigned int q1 = (unsigned int)(f1 * 65535.0f + 0.5f);
  int pos = atomicAdd(&ofs[d], 1);
  uint2 rc;
  rc.x = (unsigned int)s | ((unsigned int)I0 << 16);
  rc.y = q0 | (q1 << 16);
  recs[pos] = rc;
}

// ---------------- agg (one wave per dst node, 4 indep max chains, scalarized) ----------------
static __device__ __forceinline__ float emsg(
    const unsigned short* __restrict__ Y, unsigned int rx, unsigned int ry, int lane) {
  // rx, ry are wave-uniform (readfirstlane'd) -> address math on SALU
  int src = rx & 0xffff;
  int I0 = rx >> 16;
  float f0 = (float)(ry & 0xffff) * (1.0f / 65535.0f);
  float f1 = (float)(ry >> 16) * (1.0f / 65535.0f);
  const unsigned short* base = Y + (size_t)src * 1600 + I0 * 64 + lane;
  float y0 = bf2f(base[0]);
  float y1 = bf2f(base[64]);
  float y2 = bf2f(base[320]);
  float y3 = bf2f(base[384]);
  return (1.0f - f0) * ((1.0f - f1) * y0 + f1 * y1) +
         f0 * ((1.0f - f1) * y2 + f1 * y3);
}

__global__ __launch_bounds__(256) void agg_kernel(
    const unsigned short* __restrict__ Y, const uint2* __restrict__ recs,
    const int* __restrict__ start, const float* __restrict__ xin,
    const float* __restrict__ root, const float* __restrict__ bias,
    float* __restrict__ outp, int relu) {
  __shared__ float xl[4][64];
  const int w = threadIdx.x >> 6;
  const int lane = threadIdx.x & 63;
  const int n = blockIdx.x * 4 + w;
  xl[w][lane] = xin[((size_t)n << 6) + lane];
  __syncthreads();

  const int s = __builtin_amdgcn_readfirstlane(start[n]);
  const int e = __builtin_amdgcn_readfirstlane(start[n + 1]);
  const float NI = -__builtin_inff();
  float a0 = NI, a1 = NI, a2 = NI, a3 = NI;
  int j = s;
  for (; j + 4 <= e; j += 4) {
    uint2 r0 = recs[j];
    uint2 r1 = recs[j + 1];
    uint2 r2 = recs[j + 2];
    uint2 r3 = recs[j + 3];
    unsigned x0 = __builtin_amdgcn_readfirstlane(r0.x), y0 = __builtin_amdgcn_readfirstlane(r0.y);
    unsigned x1 = __builtin_amdgcn_readfirstlane(r1.x), y1 = __builtin_amdgcn_readfirstlane(r1.y);
    unsigned x2 = __builtin_amdgcn_readfirstlane(r2.x), y2 = __builtin_amdgcn_readfirstlane(r2.y);
    unsigned x3 = __builtin_amdgcn_readfirstlane(r3.x), y3 = __builtin_amdgcn_readfirstlane(r3.y);
    float m0 = emsg(Y, x0, y0, lane);
    float m1 = emsg(Y, x1, y1, lane);
    float m2 = emsg(Y, x2, y2, lane);
    float m3 = emsg(Y, x3, y3, lane);
    a0 = fmaxf(a0, m0);
    a1 = fmaxf(a1, m1);
    a2 = fmaxf(a2, m2);
    a3 = fmaxf(a3, m3);
  }
  for (; j < e; ++j) {
    uint2 rc = recs[j];
    unsigned rx = __builtin_amdgcn_readfirstlane(rc.x);
    unsigned ry = __builtin_amdgcn_readfirstlane(rc.y);
    a0 = fmaxf(a0, emsg(Y, rx, ry, lane));
  }
  float acc = fmaxf(fmaxf(a0, a1), fmaxf(a2, a3));
  if (s == e) acc = 0.0f;

  float r = bias[lane];
  #pragma unroll 8
  for (int i = 0; i < 64; ++i)
    r += xl[w][i] * root[(i << 6) + lane];
  r += acc;
  if (relu) r = fmaxf(r, 0.0f);
  outp[((size_t)n << 6) + lane] = r;
}

extern "C" void kernel_launch(void* const* d_in, const int* in_sizes, int n_in,
                              void* d_out, int out_size, void* d_ws, size_t ws_size,
                              hipStream_t stream) {
  const float* x = (const float*)d_in[0];
  const int* ei = (const int*)d_in[1];
  const float* ea = (const float*)d_in[2];
  const float* W1 = (const float*)d_in[3];
  const float* root1 = (const float*)d_in[4];
  const float* bias1 = (const float*)d_in[5];
  const float* W2 = (const float*)d_in[6];
  const float* root2 = (const float*)d_in[7];
  const float* bias2 = (const float*)d_in[8];
  float* out = (float*)d_out;

  const size_t yB = (size_t)N_N * 1600 * 2;        // 128,000,000
  const size_t rB = (size_t)E_N * 8;               //   5,120,000
  const size_t sB = (size_t)(N_N + 2) * 4;         //     160,008
  const size_t cB = (size_t)N_N * 4;               //     160,000
  const size_t wB = (size_t)2 * 25 * 64 * 64 * 2;  //     409,600
  const size_t bB = (size_t)1024 * 2;
  if (ws_size < yB + rB + sB + cB + wB + bB) return;

  char* p = (char*)d_ws;
  unsigned short* Y = (unsigned short*)p; p += yB;
  uint2* recs = (uint2*)p;                p += rB;
  int* startA = (int*)p;                  p += sB;
  int* cnt = (int*)p;                     p += cB;   // doubles as scatter cursor
  unsigned short* Wt = (unsigned short*)p; p += wB;  // Wt1 | Wt2
  int* bsum = (int*)p;                    p += 1024;
  int* bofs = (int*)p;
  float* h = out;  // layer-1 output lives in d_out; fully overwritten by layer 2

  unsigned short* Wt1 = Wt;
  unsigned short* Wt2 = Wt + (size_t)25 * 64 * 64;

  dim3 blk(256);

  // ---- CSR build (once, shared by both layers) + both weight transposes ----
  hipMemsetAsync(cnt, 0, cB, stream);
  wtrans_kernel<<<800, blk, 0, stream>>>(W1, W2, Wt);
  hist_kernel<<<E_N / 256, blk, 0, stream>>>(ei, cnt);
  scan1_kernel<<<SCAN_B, blk, 0, stream>>>(cnt, bsum);
  scan2_kernel<<<1, blk, 0, stream>>>(bsum, bofs);
  scan3_kernel<<<SCAN_B, blk, 0, stream>>>(cnt, bofs, startA);
  scatter_kernel<<<E_N / 256, blk, 0, stream>>>(ea, ei, cnt, recs);

  // ---- layer 1 ----
  ygemm_kernel<<<N_N / 64, blk, 0, stream>>>(x, Wt1, Y);
  agg_kernel<<<N_N / 4, blk, 0, stream>>>(Y, recs, startA, x, root1, bias1, h, 1);

  // ---- layer 2 ----
  ygemm_kernel<<<N_N / 64, blk, 0, stream>>>(h, Wt2, Y);
  agg_kernel<<<N_N / 4, blk, 0, stream>>>(Y, recs, startA, h, root2, bias2, out, 0);
}